// Round 4
// baseline (5114.841 us; speedup 1.0000x reference)
//
#include <hip/hip_runtime.h>
#include <math.h>

// Problem dims
#define NB   32      // batch
#define HD   512     // hidden = embed
#define SEQ  64      // source length
#define TSEQ 48      // target length
#define NCHUNK 250   // final gemm N chunks of 128
#define MROWS  1536  // 48*32 decode rows (only first 1504 used for loss)
#define XSTR 260     // LDS x-chunk row stride (floats)
#define BARSLOT 32   // ints per barrier counter -> 128 B, own cacheline
#define MASTER 255   // barrier master block
#define NT   512     // threads per block
#define SCOPE_AG __HIP_MEMORY_SCOPE_AGENT

typedef __bf16 bf16x8 __attribute__((ext_vector_type(8)));
typedef float f32x4 __attribute__((ext_vector_type(4)));

__device__ __forceinline__ float sigmf(float x) { return 1.0f / (1.0f + expf(-x)); }

// ---- coherent (LLC) relaxed accessors ----
// Round-6 insight: coherent 8B atomic loads for the cross-block state were a
// 256-way LLC broadcast (~6.6 GB/run of small requests, invisible to
// FETCH_SIZE). Cross-block buffers are now WRITE-ONCE arenas: producers
// store write-through (stc, lands in LLC), consumers use plain cached
// loads. A write-once address can have no stale L1/L2 copy within the
// launch; dispatch-boundary invalidation covers reuse across iterations
// (same pattern H2 has used correctly since round 1). Broadcast now fills
// each XCD's L2 once (8x) instead of hitting LLC per block (256x).
// Only block-private c-state and barrier words remain atomic.
__device__ __forceinline__ float ldc_f32(const float* p) {
  return __hip_atomic_load((float*)p, __ATOMIC_RELAXED, SCOPE_AG);
}
__device__ __forceinline__ void stc_f32(float* p, float v) {
  __hip_atomic_store(p, v, __ATOMIC_RELAXED, SCOPE_AG);
}

__global__ __launch_bounds__(256) void zero_kernel(float* p, int n) {
  int i = blockIdx.x * 256 + threadIdx.x;
  if (i < n) p[i] = 0.0f;
}

// ---- store-based grid barrier, no fences, monotonic counters ----
__device__ __forceinline__ void gbar(int* bars, int& stg) {
  int* arrv = bars;
  int* rel = bars + 256 * BARSLOT;
  __syncthreads();
  ++stg;
  if (threadIdx.x == 0) {
    asm volatile("s_waitcnt vmcnt(0)" ::: "memory");
    __hip_atomic_store(arrv + blockIdx.x * BARSLOT, stg, __ATOMIC_RELAXED, SCOPE_AG);
  }
  if (blockIdx.x == MASTER) {
    if (threadIdx.x < 256) {
      while (__hip_atomic_load(arrv + threadIdx.x * BARSLOT, __ATOMIC_RELAXED, SCOPE_AG) < stg)
        __builtin_amdgcn_s_sleep(1);
    }
    __syncthreads();
    if (threadIdx.x == 0)
      __hip_atomic_store(rel, stg, __ATOMIC_RELAXED, SCOPE_AG);
  } else {
    if (threadIdx.x == 0) {
      while (__hip_atomic_load(rel, __ATOMIC_RELAXED, SCOPE_AG) < stg)
        __builtin_amdgcn_s_sleep(1);
    }
  }
  __syncthreads();
}

// ---- write-once chain slot: version 0 is the zeroed page ----
__device__ __forceinline__ float* slot(float* z, float* ar, int t) {
  return t == 0 ? z : ar + (size_t)(t - 1) * (NB * HD);
}

// ---- compile-time job selection (no runtime-indexed arrays anywhere) ----
#define CSEL_X(J)  ((J) < 2 ? x1 : ((J) < 4 ? x2 : x3))
#define CSEL_I(J)  ((J) < 2 ? i1 : ((J) < 4 ? i2 : i3))
#define CSEL_W(J)  ((J) < 2 ? W1 : ((J) < 4 ? W2 : W3))
#define CSEL_LD(J) ((J) < 2 ? ld1 : ((J) < 4 ? ld2 : ld3))
#define CSEL_CO(J) ((J) < 2 ? co1 : ((J) < 4 ? co2 : co3))

// all staging loads are plain cached float4 now (L2-served broadcast)
#define CLOADJ(J) do {                                                        \
    const float* Xj = CSEL_X(J); const int* Ij = CSEL_I(J);                   \
    const int xo = ((J) & 1) * 256;                                           \
    _Pragma("unroll")                                                         \
    for (int it = 0; it < 4; ++it) {                                          \
      const int idx = tid + it * NT; const int bb = idx >> 6, f4 = idx & 63;  \
      const float* row = Ij ? (Xj + (size_t)Ij[bb] * HD)                      \
                            : (Xj + (size_t)bb * HD);                         \
      rg[it] = *(const float4*)(row + xo + f4 * 4);                           \
    } } while (0)

#define CSTJ(BUF) do {                                                        \
    _Pragma("unroll")                                                         \
    for (int it = 0; it < 4; ++it) {                                          \
      const int idx = tid + it * NT; const int bb = idx >> 6, f4 = idx & 63;  \
      *(float4*)&(BUF)[bb * XSTR + f4 * 4] = rg[it];                          \
    } } while (0)

#define CCOMP(J, BUF) do {                                                    \
    const float* W_ = CSEL_W(J); const int ld_ = CSEL_LD(J);                  \
    const int co_ = CSEL_CO(J) + ((J) & 1) * 256;                             \
    const float* xr = (BUF) + b * XSTR + ks * CQ;                             \
    const float* wq = W_ + co_ + ks * CQ;                                     \
    const float* w0 = wq + (size_t)(hi) * ld_;                                \
    const float* w1 = wq + (size_t)(512 + hi) * ld_;                          \
    const float* w2 = wq + (size_t)(1024 + hi) * ld_;                         \
    const float* w3 = wq + (size_t)(1536 + hi) * ld_;                         \
    _Pragma("unroll 4")                                                       \
    for (int k = 0; k < CQ; k += 4) {                                         \
      const float4 xv = *(const float4*)(xr + k);                             \
      const float4 wa = *(const float4*)(w0 + k);                             \
      const float4 wb2 = *(const float4*)(w1 + k);                            \
      const float4 wc = *(const float4*)(w2 + k);                             \
      const float4 wd = *(const float4*)(w3 + k);                             \
      a0 += xv.x*wa.x + xv.y*wa.y + xv.z*wa.z + xv.w*wa.w;                    \
      a1 += xv.x*wb2.x + xv.y*wb2.y + xv.z*wb2.z + xv.w*wb2.w;                \
      a2 += xv.x*wc.x + xv.y*wc.y + xv.z*wc.z + xv.w*wc.w;                    \
      a3 += xv.x*wd.x + xv.y*wd.y + xv.z*wd.z + xv.w*wd.w;                    \
    } } while (0)

// ---- LSTM cell stage: software-pipelined staging, compile-time jobs ----
template<int HPB, int KS, bool HAS3>
__device__ __forceinline__ void cell_stage(int blk,
    const float* x1, const int* i1, const float* W1, int ld1, int co1,
    const float* x2, const int* i2, const float* W2, int ld2, int co2,
    const float* x3, const int* i3, const float* W3, int ld3, int co3,
    const float* bias, float* cbuf, float* hout, float* hseq, float* LDSf) {
  const int tid = threadIdx.x;
  const int b = tid & 31;
  const int q = tid >> 5;              // 0..15
  const int hl = q & (HPB - 1);
  const int ks = q / HPB;              // 0..KS-1, HPB*KS == 16
  const int CQ = 256 / KS;
  const int hi = blk * HPB + hl;
  float* bufA = LDSf;
  float* bufB = LDSf + 32 * XSTR;
  float* zp = LDSf + 2 * 32 * XSTR;    // [64][33]
  float a0 = 0.f, a1 = 0.f, a2 = 0.f, a3 = 0.f;
  float4 rg[4];
  // pipeline: load J+1 into regs, compute J from LDS, store J+1 to LDS
  CLOADJ(0); CSTJ(bufA);
  __syncthreads();
  CLOADJ(1); CCOMP(0, bufA); CSTJ(bufB); __syncthreads();
  CLOADJ(2); CCOMP(1, bufB); CSTJ(bufA); __syncthreads();
  CLOADJ(3); CCOMP(2, bufA); CSTJ(bufB); __syncthreads();
  if constexpr (HAS3) {
    CLOADJ(4); CCOMP(3, bufB); CSTJ(bufA); __syncthreads();
    CLOADJ(5); CCOMP(4, bufA); CSTJ(bufB); __syncthreads();
    CCOMP(5, bufB);
  } else {
    CCOMP(3, bufB);
  }
  zp[((hl * 4 + 0) * KS + ks) * 33 + b] = a0;
  zp[((hl * 4 + 1) * KS + ks) * 33 + b] = a1;
  zp[((hl * 4 + 2) * KS + ks) * 33 + b] = a2;
  zp[((hl * 4 + 3) * KS + ks) * 33 + b] = a3;
  __syncthreads();
  if (tid < 32 * HPB) {
    const int b2 = tid & 31, h2 = tid >> 5;
    const int hi2 = blk * HPB + h2;
    float z[4];
    #pragma unroll
    for (int g = 0; g < 4; ++g) {
      float s = bias[g * 512 + hi2];
      #pragma unroll
      for (int k2 = 0; k2 < KS; ++k2) s += zp[((h2 * 4 + g) * KS + k2) * 33 + b2];
      z[g] = s;
    }
    const float ig = sigmf(z[0]), fg = sigmf(z[1]);
    const float gg = tanhf(z[2]), og = sigmf(z[3]);
    const int off = b2 * HD + hi2;
    const float c2 = fg * ldc_f32(cbuf + off) + ig * gg;
    const float hv = og * tanhf(c2);
    stc_f32(cbuf + off, c2);
    stc_f32(hout + off, hv);
    if (hseq) stc_f32(hseq + off, hv);
  }
}

#define GLOADJ(J) do {                                                        \
    const float* Xj = ((J) < 2 ? x1 : x2); const int xo = ((J) & 1) * 256;    \
    _Pragma("unroll")                                                         \
    for (int it = 0; it < 4; ++it) {                                          \
      const int idx = tid + it * NT; const int bb = idx >> 6, f4 = idx & 63;  \
      rg[it] = *(const float4*)(Xj + (size_t)bb * HD + xo + f4 * 4);          \
    } } while (0)

#define GCOMP(J, BUF) do {                                                    \
    const float* W_ = ((J) < 2 ? W1 : W2);                                    \
    const int ld_ = ((J) < 2 ? ld1 : ld2);                                    \
    const int co_ = ((J) < 2 ? co1 : co2) + ((J) & 1) * 256;                  \
    const float* xr = (BUF) + b * XSTR + ks * CQ;                             \
    const float* wp = W_ + (size_t)r * ld_ + co_ + ks * CQ;                   \
    _Pragma("unroll 4")                                                       \
    for (int k = 0; k < CQ; k += 4) {                                         \
      const float4 xv = *(const float4*)(xr + k);                             \
      const float4 wv = *(const float4*)(wp + k);                             \
      acc += xv.x*wv.x + xv.y*wv.y + xv.z*wv.z + xv.w*wv.w;                   \
    } } while (0)

// ---- tanh GEMV stage, pipelined, compile-time jobs ----
template<int RPB, int KS, bool HAS2>
__device__ __forceinline__ void gemv_stage(int blk,
    const float* x1, const float* W1, int ld1, int co1,
    const float* x2, const float* W2, int ld2, int co2,
    float* out1, float* out2, float* LDSf) {
  const int tid = threadIdx.x;
  const int b = tid & 31;
  const int q = tid >> 5;
  const int rl = q & (RPB - 1);
  const int ks = q / RPB;
  const int CQ = 256 / KS;
  const int r = blk * RPB + rl;
  float* bufA = LDSf;
  float* bufB = LDSf + 32 * XSTR;
  float* zp = LDSf + 2 * 32 * XSTR;
  float acc = 0.f;
  float4 rg[4];
  GLOADJ(0); CSTJ(bufA);
  __syncthreads();
  GLOADJ(1); GCOMP(0, bufA); CSTJ(bufB); __syncthreads();
  if constexpr (HAS2) {
    GLOADJ(2); GCOMP(1, bufB); CSTJ(bufA); __syncthreads();
    GLOADJ(3); GCOMP(2, bufA); CSTJ(bufB); __syncthreads();
    GCOMP(3, bufB);
  } else {
    GCOMP(1, bufB);
  }
  zp[(rl * KS + ks) * 33 + b] = acc;
  __syncthreads();
  if (tid < 32 * RPB) {
    const int b2 = tid & 31, rl2 = tid >> 5;
    const int r2 = blk * RPB + rl2;
    float s = 0.f;
    #pragma unroll
    for (int k2 = 0; k2 < KS; ++k2) s += zp[(rl2 * KS + k2) * 33 + b2];
    const float tv = tanhf(s);
    stc_f32(out1 + b2 * HD + r2, tv);
    if (out2) stc_f32(out2 + b2 * HD + r2, tv);
  }
}

// ---- scores: yt . H2[s,b,:] for one batch, on idle blocks in gemv1 stage ----
__device__ void scores_stage(int b, const float* yt, const float* H2,
                             float* scs_g, float* LDSf) {
  const int tid = threadIdx.x;
  float* yts = LDSf;
  float* red = LDSf + 512;
  yts[tid] = yt[(size_t)b * HD + tid];
  __syncthreads();
  const int s = tid >> 3, part = tid & 7;
  const float* hrow = H2 + (size_t)s * (NB * HD) + (size_t)b * HD + part * 64;
  const float* xr = yts + part * 64;
  float a = 0.f;
  #pragma unroll 8
  for (int k = 0; k < 64; ++k) a += xr[k] * hrow[k];
  red[tid] = a;
  __syncthreads();
  if (tid < 64) {
    float v = 0.f;
    #pragma unroll
    for (int p = 0; p < 8; ++p) v += red[tid * 8 + p];
    stc_f32(scs_g + b * 64 + tid, v);
  }
}

// ---- attn: pt + wave-parallel softmax + gaussian + context ----
__device__ void attn_stage(int b, const float* tanW, const float* w2pt,
    const float* H2, const int* elen, const float* scs_g, float* ct,
    float* LDSf) {
  const int tid = threadIdx.x;
  float* red = LDSf;
  float* ats = LDSf + 512;
  float* sc  = LDSf + 580;
  // pt = sigmoid(tanW . w2pt) * len
  red[tid] = tanW[(size_t)b * HD + tid] * w2pt[tid];
  __syncthreads();
  #pragma unroll
  for (int s2 = 256; s2 > 0; s2 >>= 1) {
    if (tid < s2) red[tid] += red[tid + s2];
    __syncthreads();
  }
  if (tid == 0) sc[0] = sigmf(red[0]) * (float)elen[b];
  __syncthreads();
  const int L = elen[b];
  const float pt = sc[0];
  if (tid < 64) {  // one wave: parallel softmax + gaussian
    float v = scs_g[b * 64 + tid];
    v = (tid < L) ? v : -3.0e38f;
    float mx = v;
    #pragma unroll
    for (int d = 1; d < 64; d <<= 1) mx = fmaxf(mx, __shfl_xor(mx, d));
    float e = (tid < L) ? expf(v - mx) : 0.f;
    float sm = e;
    #pragma unroll
    for (int d = 1; d < 64; d <<= 1) sm += __shfl_xor(sm, d);
    const float al = e / sm;
    const float dd = (float)tid - pt;
    ats[tid] = al * expf(-(dd * dd) * (1.0f / 50.0f));
  }
  __syncthreads();
  {
    const int h = tid;
    float acc = 0.f;
    #pragma unroll 8
    for (int s = 0; s < 64; ++s)
      acc += ats[s] * H2[(size_t)s * (NB * HD) + (size_t)b * HD + h];
    stc_f32(ct + b * HD + h, acc);
  }
}

struct CoopArgs {
  const int *source, *target, *elen;
  const float *src_emb, *tar_emb;
  const float *eW0, *eU0, *eb0, *eW1, *eU1, *eb1;
  const float *dW0, *dU0, *db0, *dW1, *dU1, *db1;
  const float *Wht2tan, *Wtan2pt, *Wct2ht;
  float *c0, *c1, *h0z, *h1z, *dhtz, *h0ar, *h1ar, *dhtar;
  float *tanWar, *ctar, *scsar, *H1, *H2, *dout;
  int *bars;
};

__global__ __launch_bounds__(NT) void coop_kernel(CoopArgs P) {
  __shared__ float LDSf[2 * 32 * XSTR + 2200];
  const int blk = blockIdx.x;
  int stg = 0;
  // encoder: layer0 at stage t computes h0 version t+1; layer1 (skewed by 1)
  // computes h1 version t. Write-once chains; version 0 = zeroed page.
  for (int t = 0; t <= SEQ; ++t) {
    if (blk < 128) {
      if (t < SEQ)
        cell_stage<4, 4, false>(blk,
            slot(P.h0z, P.h0ar, t), nullptr, P.eU0, 512, 0,
            P.src_emb, P.source + t * NB, P.eW0, 512, 0,
            nullptr, nullptr, nullptr, 0, 0,
            P.eb0, P.c0, slot(P.h0z, P.h0ar, t + 1),
            P.H1 + (size_t)t * NB * HD, LDSf);
    } else {
      if (t >= 1)
        cell_stage<4, 4, false>(blk - 128,
            slot(P.h1z, P.h1ar, t - 1), nullptr, P.eU1, 512, 0,
            P.H1 + (size_t)(t - 1) * NB * HD, nullptr, P.eW1, 512, 0,
            nullptr, nullptr, nullptr, 0, 0,
            P.eb1, P.c1, slot(P.h1z, P.h1ar, t),
            P.H2 + (size_t)(t - 1) * NB * HD, LDSf);
    }
    gbar(P.bars, stg);
  }
  // decoder: h0/h1 chains continue at version 64 (encoder-final)
  for (int t = 0; t < TSEQ; ++t) {
    float* h1n = slot(P.h1z, P.h1ar, 65 + t);
    cell_stage<2, 8, true>(blk,
        slot(P.h0z, P.h0ar, 64 + t), nullptr, P.dU0, 512, 0,
        P.tar_emb, P.target + t * NB, P.dW0, 1024, 0,
        slot(P.dhtz, P.dhtar, t), nullptr, P.dW0, 1024, 512,
        P.db0, P.c0, slot(P.h0z, P.h0ar, 65 + t), nullptr, LDSf);
    gbar(P.bars, stg);
    cell_stage<2, 8, false>(blk,
        slot(P.h1z, P.h1ar, 64 + t), nullptr, P.dU1, 512, 0,
        slot(P.h0z, P.h0ar, 65 + t), nullptr, P.dW1, 512, 0,
        nullptr, nullptr, nullptr, 0, 0,
        P.db1, P.c1, h1n, nullptr, LDSf);
    gbar(P.bars, stg);
    if (blk < 128)
      gemv_stage<4, 4, false>(blk, h1n, P.Wht2tan, 512, 0,
                              nullptr, nullptr, 0, 0,
                              P.tanWar + (size_t)t * NB * HD, nullptr, LDSf);
    else if (blk < 160)
      scores_stage(blk - 128, h1n, P.H2, P.scsar + (size_t)t * NB * 64, LDSf);
    gbar(P.bars, stg);
    if (blk < 32)
      attn_stage(blk, P.tanWar + (size_t)t * NB * HD, P.Wtan2pt, P.H2, P.elen,
                 P.scsar + (size_t)t * NB * 64,
                 P.ctar + (size_t)t * NB * HD, LDSf);
    gbar(P.bars, stg);
    gemv_stage<2, 8, true>(blk,
        P.ctar + (size_t)t * NB * HD, P.Wct2ht, 1024, 0,
        h1n, P.Wct2ht, 1024, 512,
        slot(P.dhtz, P.dhtar, t + 1), P.dout + (size_t)t * NB * HD, LDSf);
    gbar(P.bars, stg);
  }
}

// ---- fp32 -> bf16 conversion (RNE) for final projection inputs ----
__device__ __forceinline__ ushort f2bf(float f) {
  unsigned u = __float_as_uint(f);
  u += 0x7fffu + ((u >> 16) & 1u);
  return (ushort)(u >> 16);
}
__global__ __launch_bounds__(256) void cvt_kernel(
    const float* __restrict__ a, ushort* __restrict__ da, int na,
    const float* __restrict__ w, ushort* __restrict__ dw, int nw) {
  int i = (blockIdx.x * 256 + threadIdx.x) * 4;
  if (i < na) {
    float4 v = *(const float4*)(a + i);
    ushort4 o; o.x = f2bf(v.x); o.y = f2bf(v.y); o.z = f2bf(v.z); o.w = f2bf(v.w);
    *(ushort4*)(da + i) = o;
  } else {
    int j = i - na;
    if (j < nw) {
      float4 v = *(const float4*)(w + j);
      ushort4 o; o.x = f2bf(v.x); o.y = f2bf(v.y); o.z = f2bf(v.z); o.w = f2bf(v.w);
      *(ushort4*)(dw + j) = o;
    }
  }
}

// ---- bf16 MFMA final projection: C[1536,32000] tile 64x128/block,
// 4 waves n-split, mfma_f32_16x16x32_bf16, fused per-128-col logsumexp ----
__global__ __launch_bounds__(256) void final_gemm_bf(
    const ushort* __restrict__ Au, const ushort* __restrict__ Wu,
    const int* __restrict__ target,
    float* __restrict__ pm, float* __restrict__ pl, float* __restrict__ tlg) {
  const __bf16* A = (const __bf16*)Au;
  const __bf16* W = (const __bf16*)Wu;
  const int tid = threadIdx.x;
  const int wv = tid >> 6, lane = tid & 63;
  const int l15 = lane & 15, quad = lane >> 4;
  const int m0 = blockIdx.y * 64;
  const int nb = blockIdx.x * 128;
  const int n0 = nb + wv * 32;
  const f32x4 zf = {0.f, 0.f, 0.f, 0.f};
  f32x4 acc[4][2];
  #pragma unroll
  for (int mt = 0; mt < 4; ++mt) { acc[mt][0] = zf; acc[mt][1] = zf; }
  const __bf16* ap  = A + (size_t)(m0 + l15) * HD + quad * 8;
  const __bf16* bp0 = W + (size_t)(n0 + l15) * HD + quad * 8;
  const __bf16* bp1 = W + (size_t)(n0 + 16 + l15) * HD + quad * 8;
  #pragma unroll 2
  for (int k0 = 0; k0 < HD; k0 += 32) {
    const bf16x8 b0 = *(const bf16x8*)(bp0 + k0);
    const bf16x8 b1 = *(const bf16x8*)(bp1 + k0);
    #pragma unroll
    for (int mt = 0; mt < 4; ++mt) {
      const bf16x8 av = *(const bf16x8*)(ap + (size_t)mt * 16 * HD + k0);
      acc[mt][0] = __builtin_amdgcn_mfma_f32_16x16x32_bf16(av, b0, acc[mt][0], 0, 0, 0);
      acc[mt][1] = __builtin_amdgcn_mfma_f32_16x16x32_bf16(av, b1, acc[mt][1], 0, 0, 0);
    }
  }
  // D mapping: row_loc = mt*16 + quad*4 + r, col = n0 + nt*16 + l15
  __shared__ float red[64][5];
  __shared__ float rowm[64];
  #pragma unroll
  for (int mt = 0; mt < 4; ++mt)
    #pragma unroll
    for (int r = 0; r < 4; ++r) {
      float v = fmaxf(acc[mt][0][r], acc[mt][1][r]);
      #pragma unroll
      for (int d = 1; d < 16; d <<= 1) v = fmaxf(v, __shfl_xor(v, d));
      if (l15 == 0) red[mt * 16 + quad * 4 + r][wv] = v;
    }
  __syncthreads();
  if (tid < 64)
    rowm[tid] = fmaxf(fmaxf(red[tid][0], red[tid][1]),
                      fmaxf(red[tid][2], red[tid][3]));
  __syncthreads();
  #pragma unroll
  for (int mt = 0; mt < 4; ++mt)
    #pragma unroll
    for (int r = 0; r < 4; ++r) {
      const float mm = rowm[mt * 16 + quad * 4 + r];
      float s = expf(acc[mt][0][r] - mm) + expf(acc[mt][1][r] - mm);
      #pragma unroll
      for (int d = 1; d < 16; d <<= 1) s += __shfl_xor(s, d);
      if (l15 == 0) red[mt * 16 + quad * 4 + r][wv] = s;
    }
  __syncthreads();
  if (tid < 64) {
    const int row = m0 + tid;
    pm[(size_t)blockIdx.x * MROWS + row] = rowm[tid];
    pl[(size_t)blockIdx.x * MROWS + row] =
        red[tid][0] + red[tid][1] + red[tid][2] + red[tid][3];
  }
  #pragma unroll
  for (int mt = 0; mt < 4; ++mt) {
    const int row = m0 + mt * 16 + quad * 4;
    #pragma unroll
    for (int r = 0; r < 4; ++r) {
      const int t = (row + r) >> 5, bb = (row + r) & 31;
      if (t < TSEQ - 1) {
        const int tg = target[(t + 1) * NB + bb];
        if (n0 + l15 == tg)      tlg[row + r] = acc[mt][0][r];
        if (n0 + 16 + l15 == tg) tlg[row + r] = acc[mt][1][r];
      }
    }
  }
}

__global__ __launch_bounds__(64) void final_reduce(
    const float* __restrict__ pm, const float* __restrict__ pl,
    const float* __restrict__ tlg, const int* __restrict__ target,
    float* __restrict__ out) {
  const int b = blockIdx.x, tid = threadIdx.x;
  float lp = 0.f;
  if (tid < TSEQ - 1) {
    const int row = tid * NB + b;
    float mx = -3.0e38f;
    for (int i = 0; i < NCHUNK; ++i) mx = fmaxf(mx, pm[(size_t)i * MROWS + row]);
    float l = 0.f;
    for (int i = 0; i < NCHUNK; ++i)
      l += pl[(size_t)i * MROWS + row] * expf(pm[(size_t)i * MROWS + row] - mx);
    const float lse = mx + logf(l);
    const float msk = (target[(tid + 1) * NB + b] != 0) ? 1.f : 0.f;
    lp = (tlg[row] - lse) * msk;
  }
  #pragma unroll
  for (int off = 32; off > 0; off >>= 1) lp += __shfl_down(lp, off);
  if (tid == 0) out[b] = lp;
}

extern "C" void kernel_launch(void* const* d_in, const int* in_sizes, int n_in,
                              void* d_out, int out_size, void* d_ws, size_t ws_size,
                              hipStream_t stream) {
  const int* source = (const int*)d_in[0];
  const int* target = (const int*)d_in[1];
  const int* elen   = (const int*)d_in[2];
  const float* src_emb = (const float*)d_in[3];
  const float* tar_emb = (const float*)d_in[4];
  const float* eW0 = (const float*)d_in[5];
  const float* eU0 = (const float*)d_in[6];
  const float* eb0 = (const float*)d_in[7];
  const float* eW1 = (const float*)d_in[8];
  const float* eU1 = (const float*)d_in[9];
  const float* eb1 = (const float*)d_in[10];
  const float* dW0 = (const float*)d_in[11];
  const float* dU0 = (const float*)d_in[12];
  const float* db0 = (const float*)d_in[13];
  const float* dW1 = (const float*)d_in[14];
  const float* dU1 = (const float*)d_in[15];
  const float* db1 = (const float*)d_in[16];
  const float* Wht2tan = (const float*)d_in[17];
  const float* Wtan2pt = (const float*)d_in[18];
  const float* Wct2ht  = (const float*)d_in[19];
  const float* Wfinal  = (const float*)d_in[20];
  float* out = (float*)d_out;

  // Workspace. Zero-region first: c0,c1 + chain version-0 pages + barriers.
  float* w = (float*)d_ws;
  float* c0   = w; w += NB * HD;
  float* c1   = w; w += NB * HD;
  float* h0z  = w; w += NB * HD;   // h0 chain version 0
  float* h1z  = w; w += NB * HD;   // h1 chain version 0
  float* dhtz = w; w += NB * HD;   // dht chain version 0
  int* bars = (int*)w; w += 257 * BARSLOT;   // 256 arrival slots + 1 release
  // write-once arenas (bump-allocated, one slot per producing stage)
  float* h0ar  = w; w += (size_t)112 * NB * HD;   // versions 1..112
  float* h1ar  = w; w += (size_t)112 * NB * HD;
  float* dhtar = w; w += (size_t)48 * NB * HD;    // versions 1..48
  float* tanWar = w; w += (size_t)TSEQ * NB * HD;
  float* ctar   = w; w += (size_t)TSEQ * NB * HD;
  float* scsar  = w; w += (size_t)TSEQ * NB * 64;
  float* H1  = w; w += (size_t)SEQ * NB * HD;
  float* H2  = w; w += (size_t)SEQ * NB * HD;
  float* dout = w; w += (size_t)TSEQ * NB * HD;
  float* pm  = w; w += (size_t)NCHUNK * MROWS;
  float* pl  = w; w += (size_t)NCHUNK * MROWS;
  float* tlg = w; w += MROWS;
  ushort* Abf = (ushort*)w; w += (MROWS * HD) / 2;            // 1536x512 bf16
  ushort* Wbf = (ushort*)w; w += ((size_t)32000 * HD) / 2;    // 32000x512 bf16

  const int nzero = 5 * NB * HD + 257 * BARSLOT;
  zero_kernel<<<dim3((nzero + 255) / 256), dim3(256), 0, stream>>>((float*)d_ws, nzero);

  CoopArgs A;
  A.source = source; A.target = target; A.elen = elen;
  A.src_emb = src_emb; A.tar_emb = tar_emb;
  A.eW0 = eW0; A.eU0 = eU0; A.eb0 = eb0;
  A.eW1 = eW1; A.eU1 = eU1; A.eb1 = eb1;
  A.dW0 = dW0; A.dU0 = dU0; A.db0 = db0;
  A.dW1 = dW1; A.dU1 = dU1; A.db1 = db1;
  A.Wht2tan = Wht2tan; A.Wtan2pt = Wtan2pt; A.Wct2ht = Wct2ht;
  A.c0 = c0; A.c1 = c1;
  A.h0z = h0z; A.h1z = h1z; A.dhtz = dhtz;
  A.h0ar = h0ar; A.h1ar = h1ar; A.dhtar = dhtar;
  A.tanWar = tanWar; A.ctar = ctar; A.scsar = scsar;
  A.H1 = H1; A.H2 = H2; A.dout = dout;
  A.bars = bars;
  void* kargs[] = {&A};
  hipLaunchCooperativeKernel((void*)coop_kernel, dim3(256), dim3(NT), kargs, 0, stream);

  const int na = MROWS * HD;            // 786432
  const int nw = 32000 * HD;            // 16384000
  const int tot4 = (na + nw) / 4;
  cvt_kernel<<<dim3((tot4 + 255) / 256), dim3(256), 0, stream>>>(
      dout, Abf, na, Wfinal, Wbf, nw);
  final_gemm_bf<<<dim3(NCHUNK, MROWS / 64), dim3(256), 0, stream>>>(
      Abf, Wbf, target, pm, pl, tlg);
  final_reduce<<<dim3(NB), dim3(64), 0, stream>>>(pm, pl, tlg, target, out);

  (void)in_sizes; (void)n_in; (void)out_size; (void)ws_size;
}

// Round 6
// 4203.559 us; speedup vs baseline: 1.2168x; 1.2168x over previous
//
#include <hip/hip_runtime.h>
#include <math.h>

// Problem dims
#define NB   32      // batch
#define HD   512     // hidden = embed
#define SEQ  64      // source length
#define TSEQ 48      // target length
#define NCHUNK 250   // final gemm N chunks of 128
#define MROWS  1536  // 48*32 decode rows (only first 1504 used for loss)
#define XSTR 260     // LDS x-chunk row stride (floats)
#define BARSLOT 32   // ints per barrier counter -> 128 B, own cacheline
#define MASTER 255   // barrier master block
#define NT   512     // threads per block
#define SCOPE_AG __HIP_MEMORY_SCOPE_AGENT

typedef __bf16 bf16x8 __attribute__((ext_vector_type(8)));
typedef float f32x4 __attribute__((ext_vector_type(4)));

__device__ __forceinline__ float sigmf(float x) { return 1.0f / (1.0f + expf(-x)); }

// ---- coherent (LLC) relaxed accessors (block-private c-state, producers) ----
__device__ __forceinline__ float ldc_f32(const float* p) {
  return __hip_atomic_load((float*)p, __ATOMIC_RELAXED, SCOPE_AG);
}
__device__ __forceinline__ void stc_f32(float* p, float v) {
  __hip_atomic_store(p, v, __ATOMIC_RELAXED, SCOPE_AG);
}

__global__ __launch_bounds__(256) void zero_kernel(float* p, int n) {
  int i = blockIdx.x * 256 + threadIdx.x;
  if (i < n) p[i] = 0.0f;
}

// ---- store-based grid barrier, no fences, monotonic counters ----
__device__ __forceinline__ void gbar(int* bars, int& stg) {
  int* arrv = bars;
  int* rel = bars + 256 * BARSLOT;
  __syncthreads();
  ++stg;
  if (threadIdx.x == 0) {
    asm volatile("s_waitcnt vmcnt(0)" ::: "memory");
    __hip_atomic_store(arrv + blockIdx.x * BARSLOT, stg, __ATOMIC_RELAXED, SCOPE_AG);
  }
  if (blockIdx.x == MASTER) {
    if (threadIdx.x < 256) {
      while (__hip_atomic_load(arrv + threadIdx.x * BARSLOT, __ATOMIC_RELAXED, SCOPE_AG) < stg)
        __builtin_amdgcn_s_sleep(1);
    }
    __syncthreads();
    if (threadIdx.x == 0)
      __hip_atomic_store(rel, stg, __ATOMIC_RELAXED, SCOPE_AG);
  } else {
    if (threadIdx.x == 0) {
      while (__hip_atomic_load(rel, __ATOMIC_RELAXED, SCOPE_AG) < stg)
        __builtin_amdgcn_s_sleep(1);
    }
  }
  __syncthreads();
}

// ---- write-once chain slot: version 0 is the zeroed page ----
__device__ __forceinline__ float* slot(float* z, float* ar, int t) {
  return t == 0 ? z : ar + (size_t)(t - 1) * (NB * HD);
}

// ---- compile-time job selection (no runtime-indexed arrays anywhere) ----
#define CSEL_X(J)  ((J) < 2 ? x1 : ((J) < 4 ? x2 : x3))
#define CSEL_I(J)  ((J) < 2 ? i1 : ((J) < 4 ? i2 : i3))
#define CSEL_W(J)  ((J) < 2 ? W1 : ((J) < 4 ? W2 : W3))
#define CSEL_LD(J) ((J) < 2 ? ld1 : ((J) < 4 ? ld2 : ld3))
#define CSEL_CO(J) ((J) < 2 ? co1 : ((J) < 4 ? co2 : co3))

// staging loads: plain cached float4 (write-once arenas / embeddings)
#define CLOADJ(J) do {                                                        \
    const float* Xj = CSEL_X(J); const int* Ij = CSEL_I(J);                   \
    const int xo = ((J) & 1) * 256;                                           \
    _Pragma("unroll")                                                         \
    for (int it = 0; it < 4; ++it) {                                          \
      const int idx = tid + it * NT; const int bb = idx >> 6, f4 = idx & 63;  \
      const float* row = Ij ? (Xj + (size_t)Ij[bb] * HD)                      \
                            : (Xj + (size_t)bb * HD);                         \
      rg[it] = *(const float4*)(row + xo + f4 * 4);                           \
    } } while (0)

#define CSTJ(BUF) do {                                                        \
    _Pragma("unroll")                                                         \
    for (int it = 0; it < 4; ++it) {                                          \
      const int idx = tid + it * NT; const int bb = idx >> 6, f4 = idx & 63;  \
      *(float4*)&(BUF)[bb * XSTR + f4 * 4] = rg[it];                          \
    } } while (0)

// ---- register-tiled compute: 4 gates x 8 batches per thread ----
// The old 1x4 tile loaded 4 w-float4 + 1 x-float4 per 16 FMA with 32-way
// b-broadcast weight redundancy -> ~1.5 MB VMEM per block per cell stage ->
// L1-BW-bound at ~10us/stage (VALUBusy 16% matches). New tile: per 4-col
// iter: 4 w-float4 (coalesced across ks lanes, 4x redundancy) + 8 x-float4
// LDS -> 128 FMA. ~8x less weight traffic.
#define CCOMP(J, BUF) do {                                                    \
    const float* W_ = CSEL_W(J); const int ld_ = CSEL_LD(J);                  \
    const int co_ = CSEL_CO(J) + ((J) & 1) * 256;                             \
    const float* xb = (BUF) + (bg * 8) * XSTR + ks * CQ;                      \
    const float* wq = W_ + co_ + ks * CQ;                                     \
    _Pragma("unroll")                                                         \
    for (int i = 0; i < CQ / 4; ++i) {                                        \
      float4 wv0 = *(const float4*)(wq + (size_t)(hi) * ld_ + i * 4);         \
      float4 wv1 = *(const float4*)(wq + (size_t)(512 + hi) * ld_ + i * 4);   \
      float4 wv2 = *(const float4*)(wq + (size_t)(1024 + hi) * ld_ + i * 4);  \
      float4 wv3 = *(const float4*)(wq + (size_t)(1536 + hi) * ld_ + i * 4);  \
      _Pragma("unroll")                                                       \
      for (int bb = 0; bb < 8; ++bb) {                                        \
        const float4 xv = *(const float4*)(xb + bb * XSTR + i * 4);           \
        a[0][bb] += xv.x*wv0.x + xv.y*wv0.y + xv.z*wv0.z + xv.w*wv0.w;        \
        a[1][bb] += xv.x*wv1.x + xv.y*wv1.y + xv.z*wv1.z + xv.w*wv1.w;        \
        a[2][bb] += xv.x*wv2.x + xv.y*wv2.y + xv.z*wv2.z + xv.w*wv2.w;        \
        a[3][bb] += xv.x*wv3.x + xv.y*wv3.y + xv.z*wv3.z + xv.w*wv3.w;        \
      }                                                                       \
    } } while (0)

// ---- LSTM cell stage: pipelined staging + register-tiled GEMM ----
// thread = (ks, hl, bg): KS k-slices, HPB h-rows/block, 4 batch-groups of 8.
// Cross-ks reduce: reduce-scatter (masks 1,2,4 fold bb onto lane bits via
// cndmask-select, all register indices STATIC) + butterfly 8..KS/2.
// Lane lp<8 of each KS-group ends with the 4 gate sums for bb=lp.
template<int HPB, int KS, bool HAS3>
__device__ __forceinline__ void cell_stage(int blk,
    const float* x1, const int* i1, const float* W1, int ld1, int co1,
    const float* x2, const int* i2, const float* W2, int ld2, int co2,
    const float* x3, const int* i3, const float* W3, int ld3, int co3,
    const float* bias, float* cbuf, float* hout, float* hseq, float* LDSf) {
  const int tid = threadIdx.x;
  const int ks = tid & (KS - 1);
  const int hl = (tid / KS) & (HPB - 1);
  const int bg = tid / (KS * HPB);       // 0..3
  const int CQ = 256 / KS;               // cols per thread per job
  const int hi = blk * HPB + hl;
  float* bufA = LDSf;
  float* bufB = LDSf + 32 * XSTR;
  float a[4][8];
  #pragma unroll
  for (int g = 0; g < 4; ++g)
    #pragma unroll
    for (int bb = 0; bb < 8; ++bb) a[g][bb] = 0.f;
  float4 rg[4];
  // pipeline: load J+1 into regs, compute J from LDS, store J+1 to LDS
  CLOADJ(0); CSTJ(bufA);
  __syncthreads();
  CLOADJ(1); CCOMP(0, bufA); CSTJ(bufB); __syncthreads();
  CLOADJ(2); CCOMP(1, bufB); CSTJ(bufA); __syncthreads();
  CLOADJ(3); CCOMP(2, bufA); CSTJ(bufB); __syncthreads();
  if constexpr (HAS3) {
    CLOADJ(4); CCOMP(3, bufB); CSTJ(bufA); __syncthreads();
    CLOADJ(5); CCOMP(4, bufA); CSTJ(bufB); __syncthreads();
    CCOMP(5, bufB);
  } else {
    CCOMP(3, bufB);
  }
  // ---- cross-ks reduce-scatter + butterfly ----
  const int lp = tid & (KS - 1);
  float r2[4];
  #pragma unroll
  for (int g = 0; g < 4; ++g) {
    float t0[4], t1[2];
    #pragma unroll
    for (int j = 0; j < 4; ++j) {
      const float send = (lp & 1) ? a[g][2 * j] : a[g][2 * j + 1];
      const float keep = (lp & 1) ? a[g][2 * j + 1] : a[g][2 * j];
      t0[j] = keep + __shfl_xor(send, 1);
    }
    #pragma unroll
    for (int m = 0; m < 2; ++m) {
      const float send = (lp & 2) ? t0[2 * m] : t0[2 * m + 1];
      const float keep = (lp & 2) ? t0[2 * m + 1] : t0[2 * m];
      t1[m] = keep + __shfl_xor(send, 2);
    }
    {
      const float send = (lp & 4) ? t1[0] : t1[1];
      const float keep = (lp & 4) ? t1[1] : t1[0];
      r2[g] = keep + __shfl_xor(send, 4);
    }
    #pragma unroll
    for (int d = 8; d < KS; d <<= 1) r2[g] += __shfl_xor(r2[g], d);
  }
  if (lp < 8) {
    const int b = bg * 8 + lp;
    const float z0 = r2[0] + bias[hi];
    const float z1 = r2[1] + bias[512 + hi];
    const float z2 = r2[2] + bias[1024 + hi];
    const float z3 = r2[3] + bias[1536 + hi];
    const float ig = sigmf(z0), fg = sigmf(z1);
    const float gg = tanhf(z2), og = sigmf(z3);
    const int off = b * HD + hi;
    const float c2 = fg * ldc_f32(cbuf + off) + ig * gg;
    const float hv = og * tanhf(c2);
    stc_f32(cbuf + off, c2);
    stc_f32(hout + off, hv);
    if (hseq) stc_f32(hseq + off, hv);
  }
}

#define GLOADJ(J) do {                                                        \
    const float* Xj = ((J) < 2 ? x1 : x2); const int xo = ((J) & 1) * 256;    \
    _Pragma("unroll")                                                         \
    for (int it = 0; it < 4; ++it) {                                          \
      const int idx = tid + it * NT; const int bb = idx >> 6, f4 = idx & 63;  \
      rg[it] = *(const float4*)(Xj + (size_t)bb * HD + xo + f4 * 4);          \
    } } while (0)

#define GCOMP(J, BUF) do {                                                    \
    const float* W_ = ((J) < 2 ? W1 : W2);                                    \
    const int ld_ = ((J) < 2 ? ld1 : ld2);                                    \
    const int co_ = ((J) < 2 ? co1 : co2) + ((J) & 1) * 256;                  \
    const float* xr = (BUF) + b * XSTR + ks * CQ;                             \
    const float* wp = W_ + (size_t)r * ld_ + co_ + ks * CQ;                   \
    _Pragma("unroll 4")                                                       \
    for (int k = 0; k < CQ; k += 4) {                                         \
      const float4 xv = *(const float4*)(xr + k);                             \
      const float4 wv = *(const float4*)(wp + k);                             \
      acc += xv.x*wv.x + xv.y*wv.y + xv.z*wv.z + xv.w*wv.w;                   \
    } } while (0)

// ---- tanh GEMV stage, pipelined, compile-time jobs (unchanged) ----
template<int RPB, int KS, bool HAS2>
__device__ __forceinline__ void gemv_stage(int blk,
    const float* x1, const float* W1, int ld1, int co1,
    const float* x2, const float* W2, int ld2, int co2,
    float* out1, float* out2, float* LDSf) {
  const int tid = threadIdx.x;
  const int b = tid & 31;
  const int q = tid >> 5;
  const int rl = q & (RPB - 1);
  const int ks = q / RPB;
  const int CQ = 256 / KS;
  const int r = blk * RPB + rl;
  float* bufA = LDSf;
  float* bufB = LDSf + 32 * XSTR;
  float* zp = LDSf + 2 * 32 * XSTR;
  float acc = 0.f;
  float4 rg[4];
  GLOADJ(0); CSTJ(bufA);
  __syncthreads();
  GLOADJ(1); GCOMP(0, bufA); CSTJ(bufB); __syncthreads();
  if constexpr (HAS2) {
    GLOADJ(2); GCOMP(1, bufB); CSTJ(bufA); __syncthreads();
    GLOADJ(3); GCOMP(2, bufA); CSTJ(bufB); __syncthreads();
    GCOMP(3, bufB);
  } else {
    GCOMP(1, bufB);
  }
  zp[(rl * KS + ks) * 33 + b] = acc;
  __syncthreads();
  if (tid < 32 * RPB) {
    const int b2 = tid & 31, rl2 = tid >> 5;
    const int r2 = blk * RPB + rl2;
    float s = 0.f;
    #pragma unroll
    for (int k2 = 0; k2 < KS; ++k2) s += zp[(rl2 * KS + k2) * 33 + b2];
    const float tv = tanhf(s);
    stc_f32(out1 + b2 * HD + r2, tv);
    if (out2) stc_f32(out2 + b2 * HD + r2, tv);
  }
}

// ---- scores: yt . H2[s,b,:] for one batch, on idle blocks in gemv1 stage ----
__device__ void scores_stage(int b, const float* yt, const float* H2,
                             float* scs_g, float* LDSf) {
  const int tid = threadIdx.x;
  float* yts = LDSf;
  float* red = LDSf + 512;
  yts[tid] = yt[(size_t)b * HD + tid];
  __syncthreads();
  const int s = tid >> 3, part = tid & 7;
  const float* hrow = H2 + (size_t)s * (NB * HD) + (size_t)b * HD + part * 64;
  const float* xr = yts + part * 64;
  float a = 0.f;
  #pragma unroll 8
  for (int k = 0; k < 64; ++k) a += xr[k] * hrow[k];
  red[tid] = a;
  __syncthreads();
  if (tid < 64) {
    float v = 0.f;
    #pragma unroll
    for (int p = 0; p < 8; ++p) v += red[tid * 8 + p];
    stc_f32(scs_g + b * 64 + tid, v);
  }
}

// ---- attn: pt + wave-parallel softmax + gaussian + context ----
__device__ void attn_stage(int b, const float* tanW, const float* w2pt,
    const float* H2, const int* elen, const float* scs_g, float* ct,
    float* LDSf) {
  const int tid = threadIdx.x;
  float* red = LDSf;
  float* ats = LDSf + 512;
  float* sc  = LDSf + 580;
  // pt = sigmoid(tanW . w2pt) * len
  red[tid] = tanW[(size_t)b * HD + tid] * w2pt[tid];
  __syncthreads();
  #pragma unroll
  for (int s2 = 256; s2 > 0; s2 >>= 1) {
    if (tid < s2) red[tid] += red[tid + s2];
    __syncthreads();
  }
  if (tid == 0) sc[0] = sigmf(red[0]) * (float)elen[b];
  __syncthreads();
  const int L = elen[b];
  const float pt = sc[0];
  if (tid < 64) {  // one wave: parallel softmax + gaussian
    float v = scs_g[b * 64 + tid];
    v = (tid < L) ? v : -3.0e38f;
    float mx = v;
    #pragma unroll
    for (int d = 1; d < 64; d <<= 1) mx = fmaxf(mx, __shfl_xor(mx, d));
    float e = (tid < L) ? expf(v - mx) : 0.f;
    float sm = e;
    #pragma unroll
    for (int d = 1; d < 64; d <<= 1) sm += __shfl_xor(sm, d);
    const float al = e / sm;
    const float dd = (float)tid - pt;
    ats[tid] = al * expf(-(dd * dd) * (1.0f / 50.0f));
  }
  __syncthreads();
  {
    const int h = tid;
    float acc = 0.f;
    #pragma unroll 8
    for (int s = 0; s < 64; ++s)
      acc += ats[s] * H2[(size_t)s * (NB * HD) + (size_t)b * HD + h];
    stc_f32(ct + b * HD + h, acc);
  }
}

struct CoopArgs {
  const int *source, *target, *elen;
  const float *src_emb, *tar_emb;
  const float *eW0, *eU0, *eb0, *eW1, *eU1, *eb1;
  const float *dW0, *dU0, *db0, *dW1, *dU1, *db1;
  const float *Wht2tan, *Wtan2pt, *Wct2ht;
  float *c0, *c1, *h0z, *h1z, *dhtz, *h0ar, *h1ar, *dhtar;
  float *tanWar, *ctar, *scsar, *H1, *H2, *dout;
  int *bars;
};

__global__ __launch_bounds__(NT) void coop_kernel(CoopArgs P) {
  __shared__ float LDSf[2 * 32 * XSTR + 2200];
  const int blk = blockIdx.x;
  int stg = 0;
  // encoder: layer0 at stage t computes h0 version t+1; layer1 (skewed by 1)
  // computes h1 version t. Write-once chains; version 0 = zeroed page.
  for (int t = 0; t <= SEQ; ++t) {
    if (blk < 128) {
      if (t < SEQ)
        cell_stage<4, 32, false>(blk,
            slot(P.h0z, P.h0ar, t), nullptr, P.eU0, 512, 0,
            P.src_emb, P.source + t * NB, P.eW0, 512, 0,
            nullptr, nullptr, nullptr, 0, 0,
            P.eb0, P.c0, slot(P.h0z, P.h0ar, t + 1),
            P.H1 + (size_t)t * NB * HD, LDSf);
    } else {
      if (t >= 1)
        cell_stage<4, 32, false>(blk - 128,
            slot(P.h1z, P.h1ar, t - 1), nullptr, P.eU1, 512, 0,
            P.H1 + (size_t)(t - 1) * NB * HD, nullptr, P.eW1, 512, 0,
            nullptr, nullptr, nullptr, 0, 0,
            P.eb1, P.c1, slot(P.h1z, P.h1ar, t),
            P.H2 + (size_t)(t - 1) * NB * HD, LDSf);
    }
    gbar(P.bars, stg);
  }
  // decoder: h0/h1 chains continue at version 64 (encoder-final)
  for (int t = 0; t < TSEQ; ++t) {
    float* h1n = slot(P.h1z, P.h1ar, 65 + t);
    cell_stage<2, 64, true>(blk,
        slot(P.h0z, P.h0ar, 64 + t), nullptr, P.dU0, 512, 0,
        P.tar_emb, P.target + t * NB, P.dW0, 1024, 0,
        slot(P.dhtz, P.dhtar, t), nullptr, P.dW0, 1024, 512,
        P.db0, P.c0, slot(P.h0z, P.h0ar, 65 + t), nullptr, LDSf);
    gbar(P.bars, stg);
    cell_stage<2, 64, false>(blk,
        slot(P.h1z, P.h1ar, 64 + t), nullptr, P.dU1, 512, 0,
        slot(P.h0z, P.h0ar, 65 + t), nullptr, P.dW1, 512, 0,
        nullptr, nullptr, nullptr, 0, 0,
        P.db1, P.c1, h1n, nullptr, LDSf);
    gbar(P.bars, stg);
    if (blk < 128)
      gemv_stage<4, 4, false>(blk, h1n, P.Wht2tan, 512, 0,
                              nullptr, nullptr, 0, 0,
                              P.tanWar + (size_t)t * NB * HD, nullptr, LDSf);
    else if (blk < 160)
      scores_stage(blk - 128, h1n, P.H2, P.scsar + (size_t)t * NB * 64, LDSf);
    gbar(P.bars, stg);
    if (blk < 32)
      attn_stage(blk, P.tanWar + (size_t)t * NB * HD, P.Wtan2pt, P.H2, P.elen,
                 P.scsar + (size_t)t * NB * 64,
                 P.ctar + (size_t)t * NB * HD, LDSf);
    gbar(P.bars, stg);
    gemv_stage<2, 8, true>(blk,
        P.ctar + (size_t)t * NB * HD, P.Wct2ht, 1024, 0,
        h1n, P.Wct2ht, 1024, 512,
        slot(P.dhtz, P.dhtar, t + 1), P.dout + (size_t)t * NB * HD, LDSf);
    gbar(P.bars, stg);
  }
}

// ---- fp32 -> bf16 conversion (RNE) for final projection inputs ----
__device__ __forceinline__ ushort f2bf(float f) {
  unsigned u = __float_as_uint(f);
  u += 0x7fffu + ((u >> 16) & 1u);
  return (ushort)(u >> 16);
}
__global__ __launch_bounds__(256) void cvt_kernel(
    const float* __restrict__ a, ushort* __restrict__ da, int na,
    const float* __restrict__ w, ushort* __restrict__ dw, int nw) {
  int i = (blockIdx.x * 256 + threadIdx.x) * 4;
  if (i < na) {
    float4 v = *(const float4*)(a + i);
    ushort4 o; o.x = f2bf(v.x); o.y = f2bf(v.y); o.z = f2bf(v.z); o.w = f2bf(v.w);
    *(ushort4*)(da + i) = o;
  } else {
    int j = i - na;
    if (j < nw) {
      float4 v = *(const float4*)(w + j);
      ushort4 o; o.x = f2bf(v.x); o.y = f2bf(v.y); o.z = f2bf(v.z); o.w = f2bf(v.w);
      *(ushort4*)(dw + j) = o;
    }
  }
}

// ---- bf16 MFMA final projection: C[1536,32000] tile 64x128/block,
// 4 waves n-split, mfma_f32_16x16x32_bf16, fused per-128-col logsumexp ----
__global__ __launch_bounds__(256) void final_gemm_bf(
    const ushort* __restrict__ Au, const ushort* __restrict__ Wu,
    const int* __restrict__ target,
    float* __restrict__ pm, float* __restrict__ pl, float* __restrict__ tlg) {
  const __bf16* A = (const __bf16*)Au;
  const __bf16* W = (const __bf16*)Wu;
  const int tid = threadIdx.x;
  const int wv = tid >> 6, lane = tid & 63;
  const int l15 = lane & 15, quad = lane >> 4;
  const int m0 = blockIdx.y * 64;
  const int nb = blockIdx.x * 128;
  const int n0 = nb + wv * 32;
  const f32x4 zf = {0.f, 0.f, 0.f, 0.f};
  f32x4 acc[4][2];
  #pragma unroll
  for (int mt = 0; mt < 4; ++mt) { acc[mt][0] = zf; acc[mt][1] = zf; }
  const __bf16* ap  = A + (size_t)(m0 + l15) * HD + quad * 8;
  const __bf16* bp0 = W + (size_t)(n0 + l15) * HD + quad * 8;
  const __bf16* bp1 = W + (size_t)(n0 + 16 + l15) * HD + quad * 8;
  #pragma unroll 2
  for (int k0 = 0; k0 < HD; k0 += 32) {
    const bf16x8 b0 = *(const bf16x8*)(bp0 + k0);
    const bf16x8 b1 = *(const bf16x8*)(bp1 + k0);
    #pragma unroll
    for (int mt = 0; mt < 4; ++mt) {
      const bf16x8 av = *(const bf16x8*)(ap + (size_t)mt * 16 * HD + k0);
      acc[mt][0] = __builtin_amdgcn_mfma_f32_16x16x32_bf16(av, b0, acc[mt][0], 0, 0, 0);
      acc[mt][1] = __builtin_amdgcn_mfma_f32_16x16x32_bf16(av, b1, acc[mt][1], 0, 0, 0);
    }
  }
  // D mapping: row_loc = mt*16 + quad*4 + r, col = n0 + nt*16 + l15
  __shared__ float red[64][5];
  __shared__ float rowm[64];
  #pragma unroll
  for (int mt = 0; mt < 4; ++mt)
    #pragma unroll
    for (int r = 0; r < 4; ++r) {
      float v = fmaxf(acc[mt][0][r], acc[mt][1][r]);
      #pragma unroll
      for (int d = 1; d < 16; d <<= 1) v = fmaxf(v, __shfl_xor(v, d));
      if (l15 == 0) red[mt * 16 + quad * 4 + r][wv] = v;
    }
  __syncthreads();
  if (tid < 64)
    rowm[tid] = fmaxf(fmaxf(red[tid][0], red[tid][1]),
                      fmaxf(red[tid][2], red[tid][3]));
  __syncthreads();
  #pragma unroll
  for (int mt = 0; mt < 4; ++mt)
    #pragma unroll
    for (int r = 0; r < 4; ++r) {
      const float mm = rowm[mt * 16 + quad * 4 + r];
      float s = expf(acc[mt][0][r] - mm) + expf(acc[mt][1][r] - mm);
      #pragma unroll
      for (int d = 1; d < 16; d <<= 1) s += __shfl_xor(s, d);
      if (l15 == 0) red[mt * 16 + quad * 4 + r][wv] = s;
    }
  __syncthreads();
  if (tid < 64) {
    const int row = m0 + tid;
    pm[(size_t)blockIdx.x * MROWS + row] = rowm[tid];
    pl[(size_t)blockIdx.x * MROWS + row] =
        red[tid][0] + red[tid][1] + red[tid][2] + red[tid][3];
  }
  #pragma unroll
  for (int mt = 0; mt < 4; ++mt) {
    const int row = m0 + mt * 16 + quad * 4;
    #pragma unroll
    for (int r = 0; r < 4; ++r) {
      const int t = (row + r) >> 5, bb = (row + r) & 31;
      if (t < TSEQ - 1) {
        const int tg = target[(t + 1) * NB + bb];
        if (n0 + l15 == tg)      tlg[row + r] = acc[mt][0][r];
        if (n0 + 16 + l15 == tg) tlg[row + r] = acc[mt][1][r];
      }
    }
  }
}

__global__ __launch_bounds__(64) void final_reduce(
    const float* __restrict__ pm, const float* __restrict__ pl,
    const float* __restrict__ tlg, const int* __restrict__ target,
    float* __restrict__ out) {
  const int b = blockIdx.x, tid = threadIdx.x;
  float lp = 0.f;
  if (tid < TSEQ - 1) {
    const int row = tid * NB + b;
    float mx = -3.0e38f;
    for (int i = 0; i < NCHUNK; ++i) mx = fmaxf(mx, pm[(size_t)i * MROWS + row]);
    float l = 0.f;
    for (int i = 0; i < NCHUNK; ++i)
      l += pl[(size_t)i * MROWS + row] * expf(pm[(size_t)i * MROWS + row] - mx);
    const float lse = mx + logf(l);
    const float msk = (target[(tid + 1) * NB + b] != 0) ? 1.f : 0.f;
    lp = (tlg[row] - lse) * msk;
  }
  #pragma unroll
  for (int off = 32; off > 0; off >>= 1) lp += __shfl_down(lp, off);
  if (tid == 0) out[b] = lp;
}

extern "C" void kernel_launch(void* const* d_in, const int* in_sizes, int n_in,
                              void* d_out, int out_size, void* d_ws, size_t ws_size,
                              hipStream_t stream) {
  const int* source = (const int*)d_in[0];
  const int* target = (const int*)d_in[1];
  const int* elen   = (const int*)d_in[2];
  const float* src_emb = (const float*)d_in[3];
  const float* tar_emb = (const float*)d_in[4];
  const float* eW0 = (const float*)d_in[5];
  const float* eU0 = (const float*)d_in[6];
  const float* eb0 = (const float*)d_in[7];
  const float* eW1 = (const float*)d_in[8];
  const float* eU1 = (const float*)d_in[9];
  const float* eb1 = (const float*)d_in[10];
  const float* dW0 = (const float*)d_in[11];
  const float* dU0 = (const float*)d_in[12];
  const float* db0 = (const float*)d_in[13];
  const float* dW1 = (const float*)d_in[14];
  const float* dU1 = (const float*)d_in[15];
  const float* db1 = (const float*)d_in[16];
  const float* Wht2tan = (const float*)d_in[17];
  const float* Wtan2pt = (const float*)d_in[18];
  const float* Wct2ht  = (const float*)d_in[19];
  const float* Wfinal  = (const float*)d_in[20];
  float* out = (float*)d_out;

  // Workspace. Zero-region first: c0,c1 + chain version-0 pages + barriers.
  float* w = (float*)d_ws;
  float* c0   = w; w += NB * HD;
  float* c1   = w; w += NB * HD;
  float* h0z  = w; w += NB * HD;   // h0 chain version 0
  float* h1z  = w; w += NB * HD;   // h1 chain version 0
  float* dhtz = w; w += NB * HD;   // dht chain version 0
  int* bars = (int*)w; w += 257 * BARSLOT;   // 256 arrival slots + 1 release
  // write-once arenas (bump-allocated, one slot per producing stage)
  float* h0ar  = w; w += (size_t)112 * NB * HD;   // versions 1..112
  float* h1ar  = w; w += (size_t)112 * NB * HD;
  float* dhtar = w; w += (size_t)48 * NB * HD;    // versions 1..48
  float* tanWar = w; w += (size_t)TSEQ * NB * HD;
  float* ctar   = w; w += (size_t)TSEQ * NB * HD;
  float* scsar  = w; w += (size_t)TSEQ * NB * 64;
  float* H1  = w; w += (size_t)SEQ * NB * HD;
  float* H2  = w; w += (size_t)SEQ * NB * HD;
  float* dout = w; w += (size_t)TSEQ * NB * HD;
  float* pm  = w; w += (size_t)NCHUNK * MROWS;
  float* pl  = w; w += (size_t)NCHUNK * MROWS;
  float* tlg = w; w += MROWS;
  ushort* Abf = (ushort*)w; w += (MROWS * HD) / 2;            // 1536x512 bf16
  ushort* Wbf = (ushort*)w; w += ((size_t)32000 * HD) / 2;    // 32000x512 bf16

  const int nzero = 5 * NB * HD + 257 * BARSLOT;
  zero_kernel<<<dim3((nzero + 255) / 256), dim3(256), 0, stream>>>((float*)d_ws, nzero);

  CoopArgs A;
  A.source = source; A.target = target; A.elen = elen;
  A.src_emb = src_emb; A.tar_emb = tar_emb;
  A.eW0 = eW0; A.eU0 = eU0; A.eb0 = eb0;
  A.eW1 = eW1; A.eU1 = eU1; A.eb1 = eb1;
  A.dW0 = dW0; A.dU0 = dU0; A.db0 = db0;
  A.dW1 = dW1; A.dU1 = dU1; A.db1 = db1;
  A.Wht2tan = Wht2tan; A.Wtan2pt = Wtan2pt; A.Wct2ht = Wct2ht;
  A.c0 = c0; A.c1 = c1;
  A.h0z = h0z; A.h1z = h1z; A.dhtz = dhtz;
  A.h0ar = h0ar; A.h1ar = h1ar; A.dhtar = dhtar;
  A.tanWar = tanWar; A.ctar = ctar; A.scsar = scsar;
  A.H1 = H1; A.H2 = H2; A.dout = dout;
  A.bars = bars;
  void* kargs[] = {&A};
  hipLaunchCooperativeKernel((void*)coop_kernel, dim3(256), dim3(NT), kargs, 0, stream);

  const int na = MROWS * HD;            // 786432
  const int nw = 32000 * HD;            // 16384000
  const int tot4 = (na + nw) / 4;
  cvt_kernel<<<dim3((tot4 + 255) / 256), dim3(256), 0, stream>>>(
      dout, Abf, na, Wfinal, Wbf, nw);
  final_gemm_bf<<<dim3(NCHUNK, MROWS / 64), dim3(256), 0, stream>>>(
      Abf, Wbf, target, pm, pl, tlg);
  final_reduce<<<dim3(NB), dim3(64), 0, stream>>>(pm, pl, tlg, target, out);

  (void)in_sizes; (void)n_in; (void)out_size; (void)ws_size;
}